// Round 1
// baseline (122.175 us; speedup 1.0000x reference)
//
#include <hip/hip_runtime.h>
#include <hip/hip_bf16.h>
#include <stdint.h>

// ---------------------------------------------------------------------------
// MultiHeadCrossAttention, B=8 C=512 H=W=64 nh=8 d=64.
// Key algebra (derived from split_heads index scramble, t = h*64+w, f=t*512+c):
//   n = h>>3, dd = (h&7)*8 + (w>>3), hh = (w&7)*8 + (c>>6), ww = c&63
// Inverse: h = n*8+(dd>>3), w = (dd&7)*8 + (hh>>3), c = (hh&7)*64 + ww.
// With e = hh&7, g = hh>>3:  token j within slab (b,n):  t = n*512 + j,
//   j = (dd>>3)*64 + (dd&7)*8 + g   (so j&7 == g).
// q is broadcast over tokens -> scores rank-1:
//   scores[qq,kk] = qs[b][e*64+qq] * K2[b,n,g][e*64+kk]
//   qs = (guide@Wq^T + bq)*0.125 ;  K2 = hrsum@Wk^T + 64*bk ;
//   hrsum[b,n,g,c'] = sum_{j==g mod 8} hid[b,c',n*512+j]
// attended[qq,dd] = sum_kk softmax(scores)[qq,kk] * v_blk[e*64+kk][j(dd,g)]
//   v_blk[c][j] = sum_c' Wv[c][c'] * hid[b][c'][n*512+j] + bv[c]
// out[b][n*64+dd][g*8+e][qq]
// ---------------------------------------------------------------------------

typedef __attribute__((ext_vector_type(8))) short bf16x8_t;  // 8 bf16 in 4 VGPRs
typedef __attribute__((ext_vector_type(4))) float f32x4_t;

__device__ __forceinline__ unsigned short f2bf(float f) {
  unsigned int u = __float_as_uint(f);
  u += 0x7FFFu + ((u >> 16) & 1u);   // round-to-nearest-even
  return (unsigned short)(u >> 16);
}

// ---------------- kernel 1: Wv fp32 -> bf16 ----------------
__global__ __launch_bounds__(256) void k_wvb(const float* __restrict__ Wv,
                                             unsigned short* __restrict__ Wvb) {
  int gid = blockIdx.x * 256 + threadIdx.x;     // 65536 threads * 4 elems
  float4 v = ((const float4*)Wv)[gid];
  ushort4 o;
  o.x = f2bf(v.x); o.y = f2bf(v.y); o.z = f2bf(v.z); o.w = f2bf(v.w);
  ((ushort4*)Wvb)[gid] = o;
}

// ---------------- kernel 2: transpose hid -> XT (bf16) + hrsum (fp32) -------
// grid 512: (b,n,cb); each WG handles [64 c' x 512 j] of one slab.
__global__ __launch_bounds__(256) void k_trans(const float* __restrict__ hid,
                                               unsigned short* __restrict__ XT,
                                               float* __restrict__ hrsum) {
  int bid = blockIdx.x;
  int cb = bid & 7, n = (bid >> 3) & 7, b = bid >> 6;
  int tid = threadIdx.x;
  __shared__ float T[64][65];        // pad 65: scalar access, 2-way max conflicts
  __shared__ float hsred[64][8];

  for (int i = tid; i < 512; i += 256) ((float*)hsred)[i] = 0.f;

  float part[4][4];
#pragma unroll
  for (int m = 0; m < 4; ++m)
#pragma unroll
    for (int i = 0; i < 4; ++i) part[m][i] = 0.f;

  const int f4 = tid & 15;     // float4 index within 64-j row
  const int r0 = tid >> 4;     // row group
  const float* srcbase = hid + (size_t)(b * 512 + cb * 64) * 4096 + n * 512;
  unsigned short* xtbase = XT + (size_t)(b * 8 + n) * 512 * 512 + cb * 64;

  for (int jc = 0; jc < 8; ++jc) {
    __syncthreads();
#pragma unroll
    for (int m = 0; m < 4; ++m) {
      int r = r0 + 16 * m;
      float4 v = *(const float4*)(srcbase + (size_t)r * 4096 + jc * 64 + f4 * 4);
      T[r][f4 * 4 + 0] = v.x;  T[r][f4 * 4 + 1] = v.y;
      T[r][f4 * 4 + 2] = v.z;  T[r][f4 * 4 + 3] = v.w;
      // j = jc*64 + f4*4 + i  ->  g = (f4&1)*4 + i
      part[m][0] += v.x; part[m][1] += v.y; part[m][2] += v.z; part[m][3] += v.w;
    }
    __syncthreads();
#pragma unroll
    for (int p = 0; p < 2; ++p) {
      int jl = (tid >> 3) + p * 32;
      int o = tid & 7;
      unsigned short t0 = f2bf(T[o * 8 + 0][jl]);
      unsigned short t1 = f2bf(T[o * 8 + 1][jl]);
      unsigned short t2 = f2bf(T[o * 8 + 2][jl]);
      unsigned short t3 = f2bf(T[o * 8 + 3][jl]);
      unsigned short t4 = f2bf(T[o * 8 + 4][jl]);
      unsigned short t5 = f2bf(T[o * 8 + 5][jl]);
      unsigned short t6 = f2bf(T[o * 8 + 6][jl]);
      unsigned short t7 = f2bf(T[o * 8 + 7][jl]);
      uint4 pk;
      pk.x = (unsigned)t0 | ((unsigned)t1 << 16);
      pk.y = (unsigned)t2 | ((unsigned)t3 << 16);
      pk.z = (unsigned)t4 | ((unsigned)t5 << 16);
      pk.w = (unsigned)t6 | ((unsigned)t7 << 16);
      *(uint4*)(xtbase + (size_t)(jc * 64 + jl) * 512 + o * 8) = pk;
    }
  }
  __syncthreads();
  {
    int gbase = (tid & 1) * 4;
#pragma unroll
    for (int m = 0; m < 4; ++m) {
      int r = r0 + 16 * m;
#pragma unroll
      for (int i = 0; i < 4; ++i) atomicAdd(&hsred[r][gbase + i], part[m][i]);
    }
  }
  __syncthreads();
  float* hout = hrsum + (size_t)(b * 8 + n) * 8 * 512 + cb * 64;
  for (int i = tid; i < 512; i += 256) {
    int g = i >> 6, r = i & 63;
    hout[(size_t)g * 512 + r] = hsred[r][g];
  }
}

// ---------------- kernel 3: K2 = hrsum@Wk^T + 64*bk ; qs = (guide@Wq^T+bq)/8 -
// grid 272 = 17 row-tiles * 16 col-tiles (row-tile 16 == the 8 guide rows).
__global__ __launch_bounds__(256) void k_k2(const float* __restrict__ hrsum,
                                            const float* __restrict__ Wk,
                                            const float* __restrict__ bk,
                                            const float* __restrict__ guide,
                                            const float* __restrict__ Wq,
                                            const float* __restrict__ bq,
                                            float* __restrict__ K2,
                                            float* __restrict__ qs) {
  int bid = blockIdx.x;
  int rt = bid >> 4, ct = bid & 15;
  bool isQ = (rt == 16);
  const float* A = isQ ? guide : (hrsum + (size_t)rt * 32 * 512);
  const float* Bm = isQ ? Wq : Wk;
  int arows = isQ ? 8 : 32;
  int tid = threadIdx.x;
  __shared__ float Ah[32][36];
  __shared__ float Bh[32][36];
  int r = tid >> 3, f = tid & 7;
  int oy = (tid >> 4) * 2, ox = (tid & 15) * 2;
  float a00 = 0.f, a01 = 0.f, a10 = 0.f, a11 = 0.f;

  for (int kc = 0; kc < 16; ++kc) {
    __syncthreads();
    float4 av = (r < arows) ? *(const float4*)(A + (size_t)r * 512 + kc * 32 + f * 4)
                            : make_float4(0.f, 0.f, 0.f, 0.f);
    *(float4*)(&Ah[r][f * 4]) = av;
    float4 bv = *(const float4*)(Bm + (size_t)(ct * 32 + r) * 512 + kc * 32 + f * 4);
    *(float4*)(&Bh[r][f * 4]) = bv;
    __syncthreads();
#pragma unroll
    for (int kk = 0; kk < 32; kk += 4) {
      float4 x0 = *(float4*)(&Ah[oy][kk]);
      float4 x1 = *(float4*)(&Ah[oy + 1][kk]);
      float4 y0 = *(float4*)(&Bh[ox][kk]);
      float4 y1 = *(float4*)(&Bh[ox + 1][kk]);
      a00 += x0.x * y0.x + x0.y * y0.y + x0.z * y0.z + x0.w * y0.w;
      a01 += x0.x * y1.x + x0.y * y1.y + x0.z * y1.z + x0.w * y1.w;
      a10 += x1.x * y0.x + x1.y * y0.y + x1.z * y0.z + x1.w * y0.w;
      a11 += x1.x * y1.x + x1.y * y1.y + x1.z * y1.z + x1.w * y1.w;
    }
  }
  int c0 = ct * 32 + ox;
  if (!isQ) {
    int row0 = rt * 32 + oy;
    K2[(size_t)row0 * 512 + c0]           = a00 + 64.f * bk[c0];
    K2[(size_t)row0 * 512 + c0 + 1]       = a01 + 64.f * bk[c0 + 1];
    K2[(size_t)(row0 + 1) * 512 + c0]     = a10 + 64.f * bk[c0];
    K2[(size_t)(row0 + 1) * 512 + c0 + 1] = a11 + 64.f * bk[c0 + 1];
  } else if (oy < 8) {
    const float scale = 0.125f;
    qs[(size_t)oy * 512 + c0]           = (a00 + bq[c0]) * scale;
    qs[(size_t)oy * 512 + c0 + 1]       = (a01 + bq[c0 + 1]) * scale;
    qs[(size_t)(oy + 1) * 512 + c0]     = (a10 + bq[c0]) * scale;
    qs[(size_t)(oy + 1) * 512 + c0 + 1] = (a11 + bq[c0 + 1]) * scale;
  }
}

// ---------------- kernel 4: V-GEMM + rank-1 softmax + PV + store -------------
// grid 1024 = slab(64) * jh(2) * e(8); 256 threads = 4 waves, wave owns 64 j.
__global__ __launch_bounds__(256, 2) void k_attn(
    const unsigned short* __restrict__ XT, const unsigned short* __restrict__ Wvb,
    const float* __restrict__ K2, const float* __restrict__ qs,
    const float* __restrict__ bv, float* __restrict__ out) {
  int bid = blockIdx.x;
  int e = bid & 7;
  int jh = (bid >> 3) & 1;
  int slab = bid >> 4;
  int n = slab & 7, b = slab >> 3;

  int tid = threadIdx.x;
  int w = tid >> 6;
  int l = tid & 63;

  __shared__ __align__(16) unsigned char smem[43264];
  unsigned short* Xl = (unsigned short*)smem;            // [256][64] bf16; later Vl
  unsigned short* Wl = (unsigned short*)(smem + 32768);  // [64][64] bf16
  float* K2g = (float*)(smem + 40960);                   // [8][64]
  float* bvl = (float*)(smem + 43008);                   // [64]

  if (tid < 128) {
    int g = tid >> 4, k4 = (tid & 15) * 4;
    *(float4*)(&K2g[g * 64 + k4]) =
        *(const float4*)(K2 + (size_t)(slab * 8 + g) * 512 + e * 64 + k4);
  } else if (tid < 192) {
    int c = tid - 128;
    bvl[c] = bv[e * 64 + c];
  }

  f32x4_t acc[4][4];
#pragma unroll
  for (int i = 0; i < 4; ++i)
#pragma unroll
    for (int j = 0; j < 4; ++j) acc[i][j] = (f32x4_t){0.f, 0.f, 0.f, 0.f};

  const int lr = l >> 3, lc = l & 7;
  const int l15 = l & 15, l4 = l >> 4;
  const unsigned short* xsrc = XT + ((size_t)slab * 512 + jh * 256) * 512;
  const unsigned short* wsrc = Wvb + (size_t)e * 64 * 512;

  // ---- phase 1: v_blk[64c x 256j] = Wv[e-block] * X^T, K-loop over c' ----
  for (int kc = 0; kc < 8; ++kc) {
    __syncthreads();
#pragma unroll
    for (int i = 0; i < 8; ++i) {      // stage Xl rows (this wave's 64 j)
      int row = w * 64 + i * 8 + lr;
      uint4 v = *(const uint4*)(xsrc + (size_t)row * 512 + kc * 64 + lc * 8);
      unsigned off = row * 128 + ((lc * 16) ^ ((row & 7) << 4));
      *(uint4*)((unsigned char*)Xl + off) = v;
    }
#pragma unroll
    for (int i = 0; i < 2; ++i) {      // stage Wl
      int row = w * 16 + i * 8 + lr;
      uint4 v = *(const uint4*)(wsrc + (size_t)row * 512 + kc * 64 + lc * 8);
      unsigned off = row * 128 + ((lc * 16) ^ ((row & 7) << 4));
      *(uint4*)((unsigned char*)Wl + off) = v;
    }
    __syncthreads();
#pragma unroll
    for (int ks = 0; ks < 2; ++ks) {
      unsigned colbyte = ks * 64 + l4 * 16;
      bf16x8_t af[4], bfr[4];
#pragma unroll
      for (int mt = 0; mt < 4; ++mt) {   // A = Wv rows (m = c_loc)
        int row = mt * 16 + l15;
        unsigned off = row * 128 + (colbyte ^ ((row & 7) << 4));
        af[mt] = *(const bf16x8_t*)((unsigned char*)Wl + off);
      }
#pragma unroll
      for (int nt = 0; nt < 4; ++nt) {   // B = X rows (n = j)
        int row = w * 64 + nt * 16 + l15;
        unsigned off = row * 128 + (colbyte ^ ((row & 7) << 4));
        bfr[nt] = *(const bf16x8_t*)((unsigned char*)Xl + off);
      }
#pragma unroll
      for (int mt = 0; mt < 4; ++mt)
#pragma unroll
        for (int nt = 0; nt < 4; ++nt)
          acc[mt][nt] = __builtin_amdgcn_mfma_f32_16x16x32_bf16(
              af[mt], bfr[nt], acc[mt][nt], 0, 0, 0);
    }
  }

  // ---- phase 1.5: spill acc -> Vl[j][c] bf16 (XOR-swizzled) ----
  __syncthreads();
  unsigned short* Vl = Xl;
#pragma unroll
  for (int nt = 0; nt < 4; ++nt) {
    int row = w * 64 + nt * 16 + l15;                       // j_local
    unsigned swz = (unsigned)(((row & 7) ^ ((row >> 3) & 7)) << 4);
#pragma unroll
    for (int mt = 0; mt < 4; ++mt) {
      int c0 = mt * 16 + l4 * 4;
      float v0 = acc[mt][nt][0] + bvl[c0 + 0];
      float v1 = acc[mt][nt][1] + bvl[c0 + 1];
      float v2 = acc[mt][nt][2] + bvl[c0 + 2];
      float v3 = acc[mt][nt][3] + bvl[c0 + 3];
      uint2 pk;
      pk.x = (unsigned)f2bf(v0) | ((unsigned)f2bf(v1) << 16);
      pk.y = (unsigned)f2bf(v2) | ((unsigned)f2bf(v3) << 16);
      unsigned off = row * 128 + ((unsigned)(mt * 32 + l4 * 8) ^ swz);
      *(uint2*)((unsigned char*)Vl + off) = pk;
    }
  }
  __syncthreads();

  // ---- phase 2: per wave two g's: softmax (rank-1, in-register) + PV ----
  float alpha = qs[(size_t)b * 512 + e * 64 + l];  // lane = qq

#pragma unroll
  for (int gi = 0; gi < 2; ++gi) {
    int g = w + gi * 4;
    float mmax = -3.0e38f;
#pragma unroll 8
    for (int kk = 0; kk < 64; ++kk)
      mmax = fmaxf(mmax, alpha * K2g[g * 64 + kk]);
    float ssum = 0.f;
#pragma unroll 8
    for (int kk = 0; kk < 64; ++kk)
      ssum += __expf(alpha * K2g[g * 64 + kk] - mmax);
    float inv = 1.0f / ssum;

    f32x4_t acc2[2][4];
#pragma unroll
    for (int i = 0; i < 2; ++i)
#pragma unroll
      for (int j = 0; j < 4; ++j) acc2[i][j] = (f32x4_t){0.f, 0.f, 0.f, 0.f};

#pragma unroll
    for (int ks = 0; ks < 2; ++ks) {
      bf16x8_t va[2];
#pragma unroll
      for (int mt = 0; mt < 2; ++mt) {   // A = V2[dd][kk] = Vl[j(dd,g)][kk]
        int ddl = mt * 16 + l15;
        int row = ((ddl >> 3) << 6) + ((ddl & 7) << 3) + g;  // j_local, row&7==g
        unsigned off = row * 128 +
            ((unsigned)(ks * 64 + l4 * 16) ^ (unsigned)((((row & 7) ^ ((row >> 3) & 7))) << 4));
        va[mt] = *(const bf16x8_t*)((unsigned char*)Vl + off);
      }
      int kk0 = ks * 32 + l4 * 8;
      float4 be0 = *(float4*)(&K2g[g * 64 + kk0]);
      float4 be1 = *(float4*)(&K2g[g * 64 + kk0 + 4]);
      bf16x8_t pb[4];
#pragma unroll
      for (int nt = 0; nt < 4; ++nt) {   // B = P[kk][qq], built in registers
        int qq = nt * 16 + l15;
        float aq = __shfl(alpha, qq);
        float mq = __shfl(mmax, qq);
        float iq = __shfl(inv, qq);
        bf16x8_t p;
        p[0] = (short)f2bf(__expf(aq * be0.x - mq) * iq);
        p[1] = (short)f2bf(__expf(aq * be0.y - mq) * iq);
        p[2] = (short)f2bf(__expf(aq * be0.z - mq) * iq);
        p[3] = (short)f2bf(__expf(aq * be0.w - mq) * iq);
        p[4] = (short)f2bf(__expf(aq * be1.x - mq) * iq);
        p[5] = (short)f2bf(__expf(aq * be1.y - mq) * iq);
        p[6] = (short)f2bf(__expf(aq * be1.z - mq) * iq);
        p[7] = (short)f2bf(__expf(aq * be1.w - mq) * iq);
        pb[nt] = p;
      }
#pragma unroll
      for (int mt = 0; mt < 2; ++mt)
#pragma unroll
        for (int nt = 0; nt < 4; ++nt)
          acc2[mt][nt] = __builtin_amdgcn_mfma_f32_16x16x32_bf16(
              va[mt], pb[nt], acc2[mt][nt], 0, 0, 0);
    }
    // D[m=dd][n=qq]: stores contiguous in qq (coalesced 64B per 16 lanes)
#pragma unroll
    for (int mt = 0; mt < 2; ++mt) {
#pragma unroll
      for (int r = 0; r < 4; ++r) {
        int dd = jh * 32 + mt * 16 + l4 * 4 + r;
        size_t base = (((size_t)b * 512 + n * 64 + dd) * 64 + (g * 8 + e)) * 64;
#pragma unroll
        for (int nt = 0; nt < 4; ++nt)
          out[base + nt * 16 + l15] = acc2[mt][nt][r];
      }
    }
  }
}

// ---------------------------------------------------------------------------
extern "C" void kernel_launch(void* const* d_in, const int* in_sizes, int n_in,
                              void* d_out, int out_size, void* d_ws, size_t ws_size,
                              hipStream_t stream) {
  const float* guide = (const float*)d_in[0];
  const float* hid   = (const float*)d_in[1];
  const float* Wq    = (const float*)d_in[2];
  const float* bq    = (const float*)d_in[3];
  const float* Wk    = (const float*)d_in[4];
  const float* bk    = (const float*)d_in[5];
  const float* Wv    = (const float*)d_in[6];
  const float* bv    = (const float*)d_in[7];
  float* out = (float*)d_out;

  char* ws = (char*)d_ws;
  unsigned short* XT  = (unsigned short*)(ws);             // 33,554,432 B
  unsigned short* Wvb = (unsigned short*)(ws + 33554432);  //    524,288 B
  float* hrsum        = (float*)(ws + 34078720);           //  1,048,576 B
  float* K2           = (float*)(ws + 35127296);           //  1,048,576 B
  float* qs           = (float*)(ws + 36175872);           //     16,384 B

  k_wvb<<<256, 256, 0, stream>>>(Wv, Wvb);
  k_trans<<<512, 256, 0, stream>>>(hid, XT, hrsum);
  k_k2<<<272, 256, 0, stream>>>(hrsum, Wk, bk, guide, Wq, bq, K2, qs);
  k_attn<<<1024, 256, 0, stream>>>(XT, Wvb, K2, qs, bv, out);
}

// Round 2
// 98.453 us; speedup vs baseline: 1.2409x; 1.2409x over previous
//
#include <hip/hip_runtime.h>
#include <hip/hip_bf16.h>
#include <stdint.h>

// ---------------------------------------------------------------------------
// MultiHeadCrossAttention, B=8 C=512 H=W=64 nh=8 d=64.
// Index algebra (t = h*64+w, f = t*512+c):
//   n = h>>3, dd = (h&7)*8 + (w>>3), hh = (w&7)*8 + (c>>6), ww = c&63
// With e = hh&7, g = hh>>3: token j within slab (b,n): j = 8*dd + g.
// q broadcast over tokens -> scores rank-1:
//   scores[qq,kk] = qs[b][e*64+qq] * K2[b,n,g][e*64+kk]
//   qs = (guide@Wq^T + bq)*0.125 ; K2 = hrsum@Wk^T + 64*bk
//   hrsum[b,n,g,c'] = sum_{j==g mod 8} hid[b,c',n*512+j]
// attended[qq,dd] = sum_kk softmax(scores)[qq,kk] * V[e*64+kk][j(dd,g)]
//   V[c][j] = sum_c' Wv[c][c'] * hid[b][c'][n*512+j] + bv[c]
// out[b][n*64+dd][g*8+e][qq]
// ---------------------------------------------------------------------------

typedef __attribute__((ext_vector_type(8))) short bf16x8_t;
typedef __attribute__((ext_vector_type(4))) float f32x4_t;

__device__ __forceinline__ unsigned short f2bf(float f) {
  unsigned int u = __float_as_uint(f);
  u += 0x7FFFu + ((u >> 16) & 1u);
  return (unsigned short)(u >> 16);
}

__device__ __forceinline__ void gload16(const unsigned short* g, void* lds) {
  __builtin_amdgcn_global_load_lds(
      (const __attribute__((address_space(1))) unsigned int*)g,
      (__attribute__((address_space(3))) unsigned int*)lds, 16, 0, 0);
}

// ---------------- kernel 1: Wv fp32 -> bf16 ----------------
__global__ __launch_bounds__(256) void k_wvb(const float* __restrict__ Wv,
                                             unsigned short* __restrict__ Wvb) {
  int gid = blockIdx.x * 256 + threadIdx.x;
  float4 v = ((const float4*)Wv)[gid];
  ushort4 o;
  o.x = f2bf(v.x); o.y = f2bf(v.y); o.z = f2bf(v.z); o.w = f2bf(v.w);
  ((ushort4*)Wvb)[gid] = o;
}

// ---------------- kernel 2: transpose hid -> XT (bf16) + hrsum (fp32) -------
__global__ __launch_bounds__(256) void k_trans(const float* __restrict__ hid,
                                               unsigned short* __restrict__ XT,
                                               float* __restrict__ hrsum) {
  int bid = blockIdx.x;
  int cb = bid & 7, n = (bid >> 3) & 7, b = bid >> 6;
  int tid = threadIdx.x;
  __shared__ float T[64][65];
  __shared__ float hsred[64][8];

  for (int i = tid; i < 512; i += 256) ((float*)hsred)[i] = 0.f;

  float part[4][4];
#pragma unroll
  for (int m = 0; m < 4; ++m)
#pragma unroll
    for (int i = 0; i < 4; ++i) part[m][i] = 0.f;

  const int f4 = tid & 15;
  const int r0 = tid >> 4;
  const float* srcbase = hid + (size_t)(b * 512 + cb * 64) * 4096 + n * 512;
  unsigned short* xtbase = XT + (size_t)(b * 8 + n) * 512 * 512 + cb * 64;

  for (int jc = 0; jc < 8; ++jc) {
    __syncthreads();
#pragma unroll
    for (int m = 0; m < 4; ++m) {
      int r = r0 + 16 * m;
      float4 v = *(const float4*)(srcbase + (size_t)r * 4096 + jc * 64 + f4 * 4);
      T[r][f4 * 4 + 0] = v.x;  T[r][f4 * 4 + 1] = v.y;
      T[r][f4 * 4 + 2] = v.z;  T[r][f4 * 4 + 3] = v.w;
      part[m][0] += v.x; part[m][1] += v.y; part[m][2] += v.z; part[m][3] += v.w;
    }
    __syncthreads();
#pragma unroll
    for (int p = 0; p < 2; ++p) {
      int jl = (tid >> 3) + p * 32;
      int o = tid & 7;
      unsigned short t0 = f2bf(T[o * 8 + 0][jl]);
      unsigned short t1 = f2bf(T[o * 8 + 1][jl]);
      unsigned short t2 = f2bf(T[o * 8 + 2][jl]);
      unsigned short t3 = f2bf(T[o * 8 + 3][jl]);
      unsigned short t4 = f2bf(T[o * 8 + 4][jl]);
      unsigned short t5 = f2bf(T[o * 8 + 5][jl]);
      unsigned short t6 = f2bf(T[o * 8 + 6][jl]);
      unsigned short t7 = f2bf(T[o * 8 + 7][jl]);
      uint4 pk;
      pk.x = (unsigned)t0 | ((unsigned)t1 << 16);
      pk.y = (unsigned)t2 | ((unsigned)t3 << 16);
      pk.z = (unsigned)t4 | ((unsigned)t5 << 16);
      pk.w = (unsigned)t6 | ((unsigned)t7 << 16);
      *(uint4*)(xtbase + (size_t)(jc * 64 + jl) * 512 + o * 8) = pk;
    }
  }
  __syncthreads();
  {
    int gbase = (tid & 1) * 4;
#pragma unroll
    for (int m = 0; m < 4; ++m) {
      int r = r0 + 16 * m;
#pragma unroll
      for (int i = 0; i < 4; ++i) atomicAdd(&hsred[r][gbase + i], part[m][i]);
    }
  }
  __syncthreads();
  float* hout = hrsum + (size_t)(b * 8 + n) * 8 * 512 + cb * 64;
  for (int i = tid; i < 512; i += 256) {
    int g = i >> 6, r = i & 63;
    hout[(size_t)g * 512 + r] = hsred[r][g];
  }
}

// ---------------- kernel 3: K2 = hrsum@Wk^T + 64*bk ; qs = (guide@Wq^T+bq)/8 -
__global__ __launch_bounds__(256) void k_k2(const float* __restrict__ hrsum,
                                            const float* __restrict__ Wk,
                                            const float* __restrict__ bk,
                                            const float* __restrict__ guide,
                                            const float* __restrict__ Wq,
                                            const float* __restrict__ bq,
                                            float* __restrict__ K2,
                                            float* __restrict__ qs) {
  int bid = blockIdx.x;
  int rt = bid >> 4, ct = bid & 15;
  bool isQ = (rt == 16);
  const float* A = isQ ? guide : (hrsum + (size_t)rt * 32 * 512);
  const float* Bm = isQ ? Wq : Wk;
  int arows = isQ ? 8 : 32;
  int tid = threadIdx.x;
  __shared__ float Ah[32][36];
  __shared__ float Bh[32][36];
  int r = tid >> 3, f = tid & 7;
  int oy = (tid >> 4) * 2, ox = (tid & 15) * 2;
  float a00 = 0.f, a01 = 0.f, a10 = 0.f, a11 = 0.f;

  for (int kc = 0; kc < 16; ++kc) {
    __syncthreads();
    float4 av = (r < arows) ? *(const float4*)(A + (size_t)r * 512 + kc * 32 + f * 4)
                            : make_float4(0.f, 0.f, 0.f, 0.f);
    *(float4*)(&Ah[r][f * 4]) = av;
    float4 bv = *(const float4*)(Bm + (size_t)(ct * 32 + r) * 512 + kc * 32 + f * 4);
    *(float4*)(&Bh[r][f * 4]) = bv;
    __syncthreads();
#pragma unroll
    for (int kk = 0; kk < 32; kk += 4) {
      float4 x0 = *(float4*)(&Ah[oy][kk]);
      float4 x1 = *(float4*)(&Ah[oy + 1][kk]);
      float4 y0 = *(float4*)(&Bh[ox][kk]);
      float4 y1 = *(float4*)(&Bh[ox + 1][kk]);
      a00 += x0.x * y0.x + x0.y * y0.y + x0.z * y0.z + x0.w * y0.w;
      a01 += x0.x * y1.x + x0.y * y1.y + x0.z * y1.z + x0.w * y1.w;
      a10 += x1.x * y0.x + x1.y * y0.y + x1.z * y0.z + x1.w * y0.w;
      a11 += x1.x * y1.x + x1.y * y1.y + x1.z * y1.z + x1.w * y1.w;
    }
  }
  int c0 = ct * 32 + ox;
  if (!isQ) {
    int row0 = rt * 32 + oy;
    K2[(size_t)row0 * 512 + c0]           = a00 + 64.f * bk[c0];
    K2[(size_t)row0 * 512 + c0 + 1]       = a01 + 64.f * bk[c0 + 1];
    K2[(size_t)(row0 + 1) * 512 + c0]     = a10 + 64.f * bk[c0];
    K2[(size_t)(row0 + 1) * 512 + c0 + 1] = a11 + 64.f * bk[c0 + 1];
  } else if (oy < 8) {
    const float scale = 0.125f;
    qs[(size_t)oy * 512 + c0]           = (a00 + bq[c0]) * scale;
    qs[(size_t)oy * 512 + c0 + 1]       = (a01 + bq[c0 + 1]) * scale;
    qs[(size_t)(oy + 1) * 512 + c0]     = (a10 + bq[c0]) * scale;
    qs[(size_t)(oy + 1) * 512 + c0 + 1] = (a11 + bq[c0 + 1]) * scale;
  }
}

// ---------------- kernel 4: fused V-GEMM + rank-1 softmax + PV ---------------
// grid 512 = slab(64) * g(8); 512 threads = 8 waves. Wave w: c-rows
// [w*64,w*64+64) (== e=w) of the M=512 x N=64(dd) V-GEMM, then PV for e=w.
__global__ __launch_bounds__(512, 4) void k_fused(
    const unsigned short* __restrict__ XT, const unsigned short* __restrict__ Wvb,
    const float* __restrict__ K2, const float* __restrict__ qs,
    const float* __restrict__ bv, float* __restrict__ out) {
  int bid = blockIdx.x;
  int g = bid & 7, slab = bid >> 3;
  int n = slab & 7, b = slab >> 3;
  int tid = threadIdx.x;
  int w = tid >> 6, l = tid & 63;
  int l15 = l & 15, l4 = l >> 4, lr = l >> 3, lc = l & 7;

  __shared__ __align__(16) unsigned char smem[77824];
  unsigned char* Al = smem;                  // [512][128B] A-tile; later Vl [64][1024B]
  unsigned char* Bl = smem + 65536;          // [64][128B] B-tile
  float* K2l = (float*)(smem + 73728);       // 512 f
  float* bvl = (float*)(smem + 75776);       // 512 f

  if (tid < 128) {
    ((float4*)K2l)[tid] = ((const float4*)(K2 + (size_t)(slab * 8 + g) * 512))[tid];
  } else if (tid < 256) {
    ((float4*)bvl)[tid - 128] = ((const float4*)bv)[tid - 128];
  }

  const unsigned swzel = (unsigned)(lc ^ lr) << 3;  // pre-swizzled src col (elems)
  const unsigned short* bsrc = XT + (size_t)slab * 512 * 512;

  f32x4_t acc[4][4];
#pragma unroll
  for (int i = 0; i < 4; ++i)
#pragma unroll
    for (int j = 0; j < 4; ++j) acc[i][j] = (f32x4_t){0.f, 0.f, 0.f, 0.f};

  const int myArow = w * 64;   // A c-rows this wave stages & computes
  const int myBrow = w * 8;    // B dd-rows this wave stages

  for (int kc = 0; kc < 8; ++kc) {
    if (kc) __syncthreads();
    // stage A (Wvb rows myArow..+64, 64 c' each), pre-swizzled source
#pragma unroll
    for (int i = 0; i < 8; ++i) {
      int r = myArow + i * 8 + lr;
      gload16(Wvb + (size_t)r * 512 + kc * 64 + swzel, Al + (myArow + i * 8) * 128);
    }
    // stage B (XT rows j = 8*dd + g for dd = myBrow..+8)
    {
      int r = myBrow + lr;
      int j = 8 * r + g;
      gload16(bsrc + (size_t)j * 512 + kc * 64 + swzel, Bl + myBrow * 128);
    }
    __syncthreads();
#pragma unroll
    for (int ks = 0; ks < 2; ++ks) {
      unsigned colb = (unsigned)(ks * 64 + l4 * 16);
      bf16x8_t af[4], bfr[4];
#pragma unroll
      for (int mt = 0; mt < 4; ++mt) {
        unsigned row = (unsigned)(myArow + mt * 16 + l15);
        af[mt] = *(const bf16x8_t*)(Al + row * 128 + (colb ^ ((row & 7) << 4)));
      }
#pragma unroll
      for (int nt = 0; nt < 4; ++nt) {
        unsigned row = (unsigned)(nt * 16 + l15);
        bfr[nt] = *(const bf16x8_t*)(Bl + row * 128 + (colb ^ ((row & 7) << 4)));
      }
#pragma unroll
      for (int mt = 0; mt < 4; ++mt)
#pragma unroll
        for (int nt = 0; nt < 4; ++nt)
          acc[mt][nt] = __builtin_amdgcn_mfma_f32_16x16x32_bf16(
              af[mt], bfr[nt], acc[mt][nt], 0, 0, 0);
    }
  }

  // ---- spill V + bias -> Vl[dd][c] bf16 (XOR-swizzled), reusing Al ----
  __syncthreads();
  unsigned char* Vl = Al;
#pragma unroll
  for (int nt = 0; nt < 4; ++nt) {
    unsigned dd = (unsigned)(nt * 16 + l15);
    unsigned swz = (dd & 7) << 4;
#pragma unroll
    for (int mt = 0; mt < 4; ++mt) {
      int c0 = w * 64 + mt * 16 + l4 * 4;
      float4 bq4 = *(const float4*)(bvl + c0);
      float v0 = acc[mt][nt][0] + bq4.x;
      float v1 = acc[mt][nt][1] + bq4.y;
      float v2 = acc[mt][nt][2] + bq4.z;
      float v3 = acc[mt][nt][3] + bq4.w;
      uint2 pk;
      pk.x = (unsigned)f2bf(v0) | ((unsigned)f2bf(v1) << 16);
      pk.y = (unsigned)f2bf(v2) | ((unsigned)f2bf(v3) << 16);
      *(uint2*)(Vl + dd * 1024 + (((unsigned)(c0 * 2)) ^ swz)) = pk;
    }
  }
  __syncthreads();

  // ---- phase 2: e = w. rank-1 softmax in-register + PV MFMA ----
  const int e = w;
  float alpha = qs[(size_t)b * 512 + e * 64 + l];   // lane = qq
  float mmax = -3.0e38f;
#pragma unroll 8
  for (int kk = 0; kk < 64; ++kk)
    mmax = fmaxf(mmax, alpha * K2l[e * 64 + kk]);
  float ssum = 0.f;
#pragma unroll 8
  for (int kk = 0; kk < 64; ++kk)
    ssum += __expf(alpha * K2l[e * 64 + kk] - mmax);
  float inv = 1.0f / ssum;

  f32x4_t acc2[4][4];
#pragma unroll
  for (int i = 0; i < 4; ++i)
#pragma unroll
    for (int j = 0; j < 4; ++j) acc2[i][j] = (f32x4_t){0.f, 0.f, 0.f, 0.f};

#pragma unroll
  for (int ks = 0; ks < 2; ++ks) {
    bf16x8_t va[4];
#pragma unroll
    for (int mt = 0; mt < 4; ++mt) {     // A[dd][kk] = Vl[dd][e*64+kk]
      unsigned dd = (unsigned)(mt * 16 + l15);
      unsigned colb = (unsigned)(e * 128 + ks * 64 + l4 * 16);
      va[mt] = *(const bf16x8_t*)(Vl + dd * 1024 + (colb ^ ((dd & 7) << 4)));
    }
    int kk0 = ks * 32 + l4 * 8;
    float4 be0 = *(float4*)(&K2l[e * 64 + kk0]);
    float4 be1 = *(float4*)(&K2l[e * 64 + kk0 + 4]);
    bf16x8_t pb[4];
#pragma unroll
    for (int nt = 0; nt < 4; ++nt) {     // B[kk][qq] built in registers
      int qq = nt * 16 + l15;
      float aq = __shfl(alpha, qq);
      float mq = __shfl(mmax, qq);
      float iq = __shfl(inv, qq);
      bf16x8_t p;
      p[0] = (short)f2bf(__expf(aq * be0.x - mq) * iq);
      p[1] = (short)f2bf(__expf(aq * be0.y - mq) * iq);
      p[2] = (short)f2bf(__expf(aq * be0.z - mq) * iq);
      p[3] = (short)f2bf(__expf(aq * be0.w - mq) * iq);
      p[4] = (short)f2bf(__expf(aq * be1.x - mq) * iq);
      p[5] = (short)f2bf(__expf(aq * be1.y - mq) * iq);
      p[6] = (short)f2bf(__expf(aq * be1.z - mq) * iq);
      p[7] = (short)f2bf(__expf(aq * be1.w - mq) * iq);
      pb[nt] = p;
    }
#pragma unroll
    for (int mt = 0; mt < 4; ++mt)
#pragma unroll
      for (int nt = 0; nt < 4; ++nt)
        acc2[mt][nt] = __builtin_amdgcn_mfma_f32_16x16x32_bf16(
            va[mt], pb[nt], acc2[mt][nt], 0, 0, 0);
  }

  // ---- stores: D[m=dd][n=qq], 64B segments per 16 lanes ----
#pragma unroll
  for (int mt = 0; mt < 4; ++mt) {
#pragma unroll
    for (int r = 0; r < 4; ++r) {
      int dd = mt * 16 + l4 * 4 + r;
      size_t base = (((size_t)(b * 512 + n * 64 + dd)) * 64 + (g * 8 + e)) * 64;
#pragma unroll
      for (int nt = 0; nt < 4; ++nt)
        out[base + nt * 16 + l15] = acc2[mt][nt][r];
    }
  }
}

// ---------------------------------------------------------------------------
extern "C" void kernel_launch(void* const* d_in, const int* in_sizes, int n_in,
                              void* d_out, int out_size, void* d_ws, size_t ws_size,
                              hipStream_t stream) {
  const float* guide = (const float*)d_in[0];
  const float* hid   = (const float*)d_in[1];
  const float* Wq    = (const float*)d_in[2];
  const float* bq    = (const float*)d_in[3];
  const float* Wk    = (const float*)d_in[4];
  const float* bk    = (const float*)d_in[5];
  const float* Wv    = (const float*)d_in[6];
  const float* bv    = (const float*)d_in[7];
  float* out = (float*)d_out;

  char* ws = (char*)d_ws;
  unsigned short* XT  = (unsigned short*)(ws);             // 33,554,432 B
  unsigned short* Wvb = (unsigned short*)(ws + 33554432);  //    524,288 B
  float* hrsum        = (float*)(ws + 34078720);           //  1,048,576 B
  float* K2           = (float*)(ws + 35127296);           //  1,048,576 B
  float* qs           = (float*)(ws + 36175872);           //     16,384 B

  k_wvb<<<256, 256, 0, stream>>>(Wv, Wvb);
  k_trans<<<512, 256, 0, stream>>>(hid, XT, hrsum);
  k_k2<<<272, 256, 0, stream>>>(hrsum, Wk, bk, guide, Wq, bq, K2, qs);
  k_fused<<<512, 512, 0, stream>>>(XT, Wvb, K2, qs, bv, out);
}

// Round 3
// 96.196 us; speedup vs baseline: 1.2701x; 1.0235x over previous
//
#include <hip/hip_runtime.h>
#include <hip/hip_bf16.h>
#include <stdint.h>

// ---------------------------------------------------------------------------
// MultiHeadCrossAttention, B=8 C=512 H=W=64 nh=8 d=64.
// Index algebra (t = h*64+w, f = t*512+c):
//   n = h>>3, dd = (h&7)*8 + (w>>3), hh = (w&7)*8 + (c>>6), ww = c&63
// With e = hh&7, g = hh>>3: token j within slab (b,n): j = 8*dd + g.
// q broadcast over tokens -> scores rank-1:
//   scores[qq,kk] = qs[b][e*64+qq] * K2[b,n,g][e*64+kk]
//   qs = (guide@Wq^T + bq)*0.125 ; K2 = hrsum@Wk^T + 64*bk
//   hrsum[b,n,g,c'] = sum_{j==g mod 8} hid[b,c',n*512+j]
// attended[qq,dd] = sum_kk softmax(scores)[qq,kk] * V[e*64+kk][j(dd,g)]
//   V[c][j] = sum_c' Wv[c][c'] * hid[b][c'][n*512+j] + bv[c]
// out[b][n*64+dd][g*8+e][qq]
// ---------------------------------------------------------------------------

typedef __attribute__((ext_vector_type(8))) short bf16x8_t;
typedef __attribute__((ext_vector_type(4))) float f32x4_t;

__device__ __forceinline__ unsigned short f2bf(float f) {
  unsigned int u = __float_as_uint(f);
  u += 0x7FFFu + ((u >> 16) & 1u);
  return (unsigned short)(u >> 16);
}

__device__ __forceinline__ void gload16(const void* g, void* lds) {
  __builtin_amdgcn_global_load_lds(
      (const __attribute__((address_space(1))) unsigned int*)g,
      (__attribute__((address_space(3))) unsigned int*)lds, 16, 0, 0);
}

// ---------------- kernel 2: transpose hid -> XT (bf16) + hrsum (fp32) -------
// blocks [0,512): transpose+hrsum. blocks [512,528): Wv fp32->bf16 convert.
__global__ __launch_bounds__(256) void k_trans(const float* __restrict__ hid,
                                               unsigned short* __restrict__ XT,
                                               float* __restrict__ hrsum,
                                               const float* __restrict__ Wv,
                                               unsigned short* __restrict__ Wvb) {
  int bid = blockIdx.x;
  int tid = threadIdx.x;
  if (bid >= 512) {
    int blk = bid - 512;
#pragma unroll
    for (int i = 0; i < 16; ++i) {
      int idx = blk * 4096 + i * 256 + tid;
      float4 v = ((const float4*)Wv)[idx];
      ushort4 o;
      o.x = f2bf(v.x); o.y = f2bf(v.y); o.z = f2bf(v.z); o.w = f2bf(v.w);
      ((ushort4*)Wvb)[idx] = o;
    }
    return;
  }
  int cb = bid & 7, n = (bid >> 3) & 7, b = bid >> 6;
  __shared__ float T[64][65];
  __shared__ float hsred[64][8];

  for (int i = tid; i < 512; i += 256) ((float*)hsred)[i] = 0.f;

  float part[4][4];
#pragma unroll
  for (int m = 0; m < 4; ++m)
#pragma unroll
    for (int i = 0; i < 4; ++i) part[m][i] = 0.f;

  const int f4 = tid & 15;
  const int r0 = tid >> 4;
  const float* srcbase = hid + (size_t)(b * 512 + cb * 64) * 4096 + n * 512;
  unsigned short* xtbase = XT + (size_t)(b * 8 + n) * 512 * 512 + cb * 64;

  for (int jc = 0; jc < 8; ++jc) {
    __syncthreads();
#pragma unroll
    for (int m = 0; m < 4; ++m) {
      int r = r0 + 16 * m;
      float4 v = *(const float4*)(srcbase + (size_t)r * 4096 + jc * 64 + f4 * 4);
      T[r][f4 * 4 + 0] = v.x;  T[r][f4 * 4 + 1] = v.y;
      T[r][f4 * 4 + 2] = v.z;  T[r][f4 * 4 + 3] = v.w;
      part[m][0] += v.x; part[m][1] += v.y; part[m][2] += v.z; part[m][3] += v.w;
    }
    __syncthreads();
#pragma unroll
    for (int p = 0; p < 2; ++p) {
      int jl = (tid >> 3) + p * 32;
      int o = tid & 7;
      unsigned short t0 = f2bf(T[o * 8 + 0][jl]);
      unsigned short t1 = f2bf(T[o * 8 + 1][jl]);
      unsigned short t2 = f2bf(T[o * 8 + 2][jl]);
      unsigned short t3 = f2bf(T[o * 8 + 3][jl]);
      unsigned short t4 = f2bf(T[o * 8 + 4][jl]);
      unsigned short t5 = f2bf(T[o * 8 + 5][jl]);
      unsigned short t6 = f2bf(T[o * 8 + 6][jl]);
      unsigned short t7 = f2bf(T[o * 8 + 7][jl]);
      uint4 pk;
      pk.x = (unsigned)t0 | ((unsigned)t1 << 16);
      pk.y = (unsigned)t2 | ((unsigned)t3 << 16);
      pk.z = (unsigned)t4 | ((unsigned)t5 << 16);
      pk.w = (unsigned)t6 | ((unsigned)t7 << 16);
      *(uint4*)(xtbase + (size_t)(jc * 64 + jl) * 512 + o * 8) = pk;
    }
  }
  __syncthreads();
  {
    int gbase = (tid & 1) * 4;
#pragma unroll
    for (int m = 0; m < 4; ++m) {
      int r = r0 + 16 * m;
#pragma unroll
      for (int i = 0; i < 4; ++i) atomicAdd(&hsred[r][gbase + i], part[m][i]);
    }
  }
  __syncthreads();
  float* hout = hrsum + (size_t)(b * 8 + n) * 8 * 512 + cb * 64;
  for (int i = tid; i < 512; i += 256) {
    int g = i >> 6, r = i & 63;
    hout[(size_t)g * 512 + r] = hsred[r][g];
  }
}

// ---------------- kernel 3: K2 = hrsum@Wk^T + 64*bk ; qs = (guide@Wq^T+bq)/8 -
__global__ __launch_bounds__(256) void k_k2(const float* __restrict__ hrsum,
                                            const float* __restrict__ Wk,
                                            const float* __restrict__ bk,
                                            const float* __restrict__ guide,
                                            const float* __restrict__ Wq,
                                            const float* __restrict__ bq,
                                            float* __restrict__ K2,
                                            float* __restrict__ qs) {
  int bid = blockIdx.x;
  int rt = bid >> 4, ct = bid & 15;
  bool isQ = (rt == 16);
  const float* A = isQ ? guide : (hrsum + (size_t)rt * 32 * 512);
  const float* Bm = isQ ? Wq : Wk;
  int arows = isQ ? 8 : 32;
  int tid = threadIdx.x;
  __shared__ float Ah[32][36];
  __shared__ float Bh[32][36];
  int r = tid >> 3, f = tid & 7;
  int oy = (tid >> 4) * 2, ox = (tid & 15) * 2;
  float a00 = 0.f, a01 = 0.f, a10 = 0.f, a11 = 0.f;

  for (int kc = 0; kc < 16; ++kc) {
    __syncthreads();
    float4 av = (r < arows) ? *(const float4*)(A + (size_t)r * 512 + kc * 32 + f * 4)
                            : make_float4(0.f, 0.f, 0.f, 0.f);
    *(float4*)(&Ah[r][f * 4]) = av;
    float4 bv = *(const float4*)(Bm + (size_t)(ct * 32 + r) * 512 + kc * 32 + f * 4);
    *(float4*)(&Bh[r][f * 4]) = bv;
    __syncthreads();
#pragma unroll
    for (int kk = 0; kk < 32; kk += 4) {
      float4 x0 = *(float4*)(&Ah[oy][kk]);
      float4 x1 = *(float4*)(&Ah[oy + 1][kk]);
      float4 y0 = *(float4*)(&Bh[ox][kk]);
      float4 y1 = *(float4*)(&Bh[ox + 1][kk]);
      a00 += x0.x * y0.x + x0.y * y0.y + x0.z * y0.z + x0.w * y0.w;
      a01 += x0.x * y1.x + x0.y * y1.y + x0.z * y1.z + x0.w * y1.w;
      a10 += x1.x * y0.x + x1.y * y0.y + x1.z * y0.z + x1.w * y0.w;
      a11 += x1.x * y1.x + x1.y * y1.y + x1.z * y1.z + x1.w * y1.w;
    }
  }
  int c0 = ct * 32 + ox;
  if (!isQ) {
    int row0 = rt * 32 + oy;
    K2[(size_t)row0 * 512 + c0]           = a00 + 64.f * bk[c0];
    K2[(size_t)row0 * 512 + c0 + 1]       = a01 + 64.f * bk[c0 + 1];
    K2[(size_t)(row0 + 1) * 512 + c0]     = a10 + 64.f * bk[c0];
    K2[(size_t)(row0 + 1) * 512 + c0 + 1] = a11 + 64.f * bk[c0 + 1];
  } else if (oy < 8) {
    const float scale = 0.125f;
    qs[(size_t)oy * 512 + c0]           = (a00 + bq[c0]) * scale;
    qs[(size_t)oy * 512 + c0 + 1]       = (a01 + bq[c0 + 1]) * scale;
    qs[(size_t)(oy + 1) * 512 + c0]     = (a10 + bq[c0]) * scale;
    qs[(size_t)(oy + 1) * 512 + c0 + 1] = (a11 + bq[c0 + 1]) * scale;
  }
}

// ---------------- kernel 4: fused V-GEMM + rank-1 softmax + PV ---------------
// grid 512 = slab(64) * g(8); 512 threads = 8 waves. Double-buffered LDS,
// counted vmcnt(9): next tile's 9 global_load_lds stay in flight across the
// barrier (T3/T4 minimum pipeline). Never __syncthreads in the K-loop.
// LDS map: A0 [0,64K) A1 [64K,128K) B0 [128K,+8K) B1 [136K,+8K)
//          K2l @147456 (2KB)  bvl @149504 (2KB)   total 151552 B.
__global__ __launch_bounds__(512, 2) void k_fused(
    const unsigned short* __restrict__ XT, const unsigned short* __restrict__ Wvb,
    const float* __restrict__ K2, const float* __restrict__ qs,
    const float* __restrict__ bv, float* __restrict__ out) {
  int bid = blockIdx.x;
  int g = bid & 7, slab = bid >> 3;
  int n = slab & 7, b = slab >> 3;
  int tid = threadIdx.x;
  int w = tid >> 6, l = tid & 63;
  int l15 = l & 15, l4 = l >> 4, lr = l >> 3, lc = l & 7;

  __shared__ __align__(16) unsigned char smem[151552];
  float* K2l = (float*)(smem + 147456);
  float* bvl = (float*)(smem + 149504);

  const unsigned swzel = (unsigned)((lc ^ lr) << 3);  // pre-swizzled src col (elems)
  const unsigned short* bsrc = XT + (size_t)slab * 512 * 512;
  const int myArow = w * 64;
  const int myBrow = w * 8;

  // K2 row + bv via global_load_lds (keeps per-wave vmcnt accounting uniform:
  // these are the oldest ops; vmcnt(9) at kc=0 also covers them).
  if (w < 2) {
    gload16(K2 + (size_t)(slab * 8 + g) * 512 + w * 256 + l * 4,
            (unsigned char*)K2l + w * 1024);
  } else if (w < 4) {
    gload16(bv + (w - 2) * 256 + l * 4, (unsigned char*)bvl + (w - 2) * 1024);
  }

#define STAGE(kc, buf)                                                          \
  do {                                                                          \
    unsigned char* Ab_ = smem + (buf)*65536;                                    \
    unsigned char* Bb_ = smem + 131072 + (buf)*8192;                            \
    _Pragma("unroll")                                                           \
    for (int i_ = 0; i_ < 8; ++i_) {                                            \
      int r_ = myArow + i_ * 8 + lr;                                            \
      gload16(Wvb + (size_t)r_ * 512 + (kc)*64 + swzel,                         \
              Ab_ + (myArow + i_ * 8) * 128);                                   \
    }                                                                           \
    int rb_ = myBrow + lr;                                                      \
    gload16(bsrc + (size_t)(8 * rb_ + g) * 512 + (kc)*64 + swzel,               \
            Bb_ + myBrow * 128);                                                \
  } while (0)

  f32x4_t acc[4][4];
#pragma unroll
  for (int i = 0; i < 4; ++i)
#pragma unroll
    for (int j = 0; j < 4; ++j) acc[i][j] = (f32x4_t){0.f, 0.f, 0.f, 0.f};

  STAGE(0, 0);
  STAGE(1, 1);

#pragma unroll
  for (int kc = 0; kc < 8; ++kc) {
    if (kc < 7) asm volatile("s_waitcnt vmcnt(9)" ::: "memory");
    else        asm volatile("s_waitcnt vmcnt(0)" ::: "memory");
    __builtin_amdgcn_s_barrier();
    {
      unsigned char* Ab = smem + (kc & 1) * 65536;
      unsigned char* Bb = smem + 131072 + (kc & 1) * 8192;
#pragma unroll
      for (int ks = 0; ks < 2; ++ks) {
        unsigned colb = (unsigned)(ks * 64 + l4 * 16);
        bf16x8_t af[4], bfr[4];
#pragma unroll
        for (int mt = 0; mt < 4; ++mt) {
          unsigned row = (unsigned)(myArow + mt * 16 + l15);
          af[mt] = *(const bf16x8_t*)(Ab + row * 128 + (colb ^ ((row & 7) << 4)));
        }
#pragma unroll
        for (int nt = 0; nt < 4; ++nt) {
          unsigned row = (unsigned)(nt * 16 + l15);
          bfr[nt] = *(const bf16x8_t*)(Bb + row * 128 + (colb ^ ((row & 7) << 4)));
        }
#pragma unroll
        for (int mt = 0; mt < 4; ++mt)
#pragma unroll
          for (int nt = 0; nt < 4; ++nt)
            acc[mt][nt] = __builtin_amdgcn_mfma_f32_16x16x32_bf16(
                af[mt], bfr[nt], acc[mt][nt], 0, 0, 0);
      }
    }
    __builtin_amdgcn_s_barrier();
    if (kc < 6) {
      if ((kc & 1) == 0) STAGE(kc + 2, 0);
      else               STAGE(kc + 2, 1);
    }
  }
#undef STAGE

  // ---- spill V + bias -> Vl[dd][c] bf16 (XOR-swizzled), reusing A-buf0 ----
  // (all waves passed the kc=6 end-barrier; buf0 no longer read)
  unsigned char* Vl = smem;
#pragma unroll
  for (int nt = 0; nt < 4; ++nt) {
    unsigned dd = (unsigned)(nt * 16 + l15);
    unsigned swz = (dd & 7) << 4;
#pragma unroll
    for (int mt = 0; mt < 4; ++mt) {
      int c0 = w * 64 + mt * 16 + l4 * 4;
      float4 bq4 = *(const float4*)(bvl + c0);
      float v0 = acc[mt][nt][0] + bq4.x;
      float v1 = acc[mt][nt][1] + bq4.y;
      float v2 = acc[mt][nt][2] + bq4.z;
      float v3 = acc[mt][nt][3] + bq4.w;
      uint2 pk;
      pk.x = (unsigned)f2bf(v0) | ((unsigned)f2bf(v1) << 16);
      pk.y = (unsigned)f2bf(v2) | ((unsigned)f2bf(v3) << 16);
      *(uint2*)(Vl + dd * 1024 + (((unsigned)(c0 * 2)) ^ swz)) = pk;
    }
  }
  __syncthreads();

  // ---- phase 2: e = w. rank-1 softmax in-register + PV MFMA ----
  const int e = w;
  float alpha = qs[(size_t)b * 512 + e * 64 + l];   // lane = qq
  float mmax = -3.0e38f;
#pragma unroll 8
  for (int kk = 0; kk < 64; ++kk)
    mmax = fmaxf(mmax, alpha * K2l[e * 64 + kk]);
  float ssum = 0.f;
#pragma unroll 8
  for (int kk = 0; kk < 64; ++kk)
    ssum += __expf(alpha * K2l[e * 64 + kk] - mmax);
  float inv = 1.0f / ssum;

  f32x4_t acc2[4][4];
#pragma unroll
  for (int i = 0; i < 4; ++i)
#pragma unroll
    for (int j = 0; j < 4; ++j) acc2[i][j] = (f32x4_t){0.f, 0.f, 0.f, 0.f};

#pragma unroll
  for (int ks = 0; ks < 2; ++ks) {
    bf16x8_t va[4];
#pragma unroll
    for (int mt = 0; mt < 4; ++mt) {     // A[dd][kk] = Vl[dd][e*64+kk]
      unsigned dd = (unsigned)(mt * 16 + l15);
      unsigned colb = (unsigned)(e * 128 + ks * 64 + l4 * 16);
      va[mt] = *(const bf16x8_t*)(Vl + dd * 1024 + (colb ^ ((dd & 7) << 4)));
    }
    int kk0 = ks * 32 + l4 * 8;
    float4 be0 = *(float4*)(&K2l[e * 64 + kk0]);
    float4 be1 = *(float4*)(&K2l[e * 64 + kk0 + 4]);
    bf16x8_t pb[4];
#pragma unroll
    for (int nt = 0; nt < 4; ++nt) {     // B[kk][qq] built in registers
      int qq = nt * 16 + l15;
      float aq = __shfl(alpha, qq);
      float mq = __shfl(mmax, qq);
      float iq = __shfl(inv, qq);
      bf16x8_t p;
      p[0] = (short)f2bf(__expf(aq * be0.x - mq) * iq);
      p[1] = (short)f2bf(__expf(aq * be0.y - mq) * iq);
      p[2] = (short)f2bf(__expf(aq * be0.z - mq) * iq);
      p[3] = (short)f2bf(__expf(aq * be0.w - mq) * iq);
      p[4] = (short)f2bf(__expf(aq * be1.x - mq) * iq);
      p[5] = (short)f2bf(__expf(aq * be1.y - mq) * iq);
      p[6] = (short)f2bf(__expf(aq * be1.z - mq) * iq);
      p[7] = (short)f2bf(__expf(aq * be1.w - mq) * iq);
      pb[nt] = p;
    }
#pragma unroll
    for (int mt = 0; mt < 4; ++mt)
#pragma unroll
      for (int nt = 0; nt < 4; ++nt)
        acc2[mt][nt] = __builtin_amdgcn_mfma_f32_16x16x32_bf16(
            va[mt], pb[nt], acc2[mt][nt], 0, 0, 0);
  }

  // ---- stores: D[m=dd][n=qq], contiguous 64B per 16 lanes ----
#pragma unroll
  for (int mt = 0; mt < 4; ++mt) {
#pragma unroll
    for (int r = 0; r < 4; ++r) {
      int dd = mt * 16 + l4 * 4 + r;
      size_t base = (((size_t)(b * 512 + n * 64 + dd)) * 64 + (g * 8 + e)) * 64;
#pragma unroll
      for (int nt = 0; nt < 4; ++nt)
        out[base + nt * 16 + l15] = acc2[mt][nt][r];
    }
  }
}

// ---------------------------------------------------------------------------
extern "C" void kernel_launch(void* const* d_in, const int* in_sizes, int n_in,
                              void* d_out, int out_size, void* d_ws, size_t ws_size,
                              hipStream_t stream) {
  const float* guide = (const float*)d_in[0];
  const float* hid   = (const float*)d_in[1];
  const float* Wq    = (const float*)d_in[2];
  const float* bq    = (const float*)d_in[3];
  const float* Wk    = (const float*)d_in[4];
  const float* bk    = (const float*)d_in[5];
  const float* Wv    = (const float*)d_in[6];
  const float* bv    = (const float*)d_in[7];
  float* out = (float*)d_out;

  char* ws = (char*)d_ws;
  unsigned short* XT  = (unsigned short*)(ws);             // 33,554,432 B
  unsigned short* Wvb = (unsigned short*)(ws + 33554432);  //    524,288 B
  float* hrsum        = (float*)(ws + 34078720);           //  1,048,576 B
  float* K2           = (float*)(ws + 35127296);           //  1,048,576 B
  float* qs           = (float*)(ws + 36175872);           //     16,384 B

  k_trans<<<528, 256, 0, stream>>>(hid, XT, hrsum, Wv, Wvb);
  k_k2<<<272, 256, 0, stream>>>(hrsum, Wk, bk, guide, Wq, bq, K2, qs);
  k_fused<<<512, 512, 0, stream>>>(XT, Wvb, K2, qs, bv, out);
}

// Round 4
// 95.634 us; speedup vs baseline: 1.2775x; 1.0059x over previous
//
#include <hip/hip_runtime.h>
#include <hip/hip_bf16.h>
#include <stdint.h>

// ---------------------------------------------------------------------------
// MultiHeadCrossAttention, B=8 C=512 H=W=64 nh=8 d=64.
// Index algebra (t = h*64+w, f = t*512+c):
//   n = h>>3, dd = (h&7)*8 + (w>>3), hh = (w&7)*8 + (c>>6), ww = c&63
// With e = hh&7, g = hh>>3: token j within slab (b,n): j = 8*dd + g.
// q broadcast over tokens -> scores rank-1:
//   scores[qq,kk] = qs[b][e*64+qq] * K2[b,n,g][e*64+kk]
//   qs = (guide@Wq^T + bq)*0.125 ; K2 = hrsum@Wk^T + 64*bk
//   hrsum[b,n,g,c'] = sum_{j==g mod 8} hid[b,c',n*512+j]
// attended[qq,dd] = sum_kk softmax(scores)[qq,kk] * V[e*64+kk][j(dd,g)]
//   V[c][j] = sum_c' Wv[c][c'] * hid[b][c'][n*512+j] + bv[c]
// out[b][n*64+dd][g*8+e][qq]
//
// k_fused structure (r4): wave w == head-block e. A (Wvb rows) is wave-private
// -> reg-loaded from L2, one K32-step prefetch ahead. B (XT rows, shared by
// all waves) double-buffered in LDS via global_load_lds + counted vmcnt.
// V stays wave-local: spilled to an 8KB private LDS slice, PV needs no
// cross-wave barrier. LDS 80KB -> 2 blocks/CU.
// ---------------------------------------------------------------------------

typedef __attribute__((ext_vector_type(8))) short bf16x8_t;
typedef __attribute__((ext_vector_type(4))) float f32x4_t;

__device__ __forceinline__ unsigned short f2bf(float f) {
  unsigned int u = __float_as_uint(f);
  u += 0x7FFFu + ((u >> 16) & 1u);
  return (unsigned short)(u >> 16);
}

__device__ __forceinline__ void gload16(const void* g, void* lds) {
  __builtin_amdgcn_global_load_lds(
      (const __attribute__((address_space(1))) unsigned int*)g,
      (__attribute__((address_space(3))) unsigned int*)lds, 16, 0, 0);
}

// ---------------- kernel 2: transpose hid -> XT (bf16) + hrsum (fp32) -------
// blocks [0,512): transpose+hrsum. blocks [512,528): Wv fp32->bf16 convert.
__global__ __launch_bounds__(256) void k_trans(const float* __restrict__ hid,
                                               unsigned short* __restrict__ XT,
                                               float* __restrict__ hrsum,
                                               const float* __restrict__ Wv,
                                               unsigned short* __restrict__ Wvb) {
  int bid = blockIdx.x;
  int tid = threadIdx.x;
  if (bid >= 512) {
    int blk = bid - 512;
#pragma unroll
    for (int i = 0; i < 16; ++i) {
      int idx = blk * 4096 + i * 256 + tid;
      float4 v = ((const float4*)Wv)[idx];
      ushort4 o;
      o.x = f2bf(v.x); o.y = f2bf(v.y); o.z = f2bf(v.z); o.w = f2bf(v.w);
      ((ushort4*)Wvb)[idx] = o;
    }
    return;
  }
  int cb = bid & 7, n = (bid >> 3) & 7, b = bid >> 6;
  __shared__ float T[64][65];
  __shared__ float hsred[64][8];

  for (int i = tid; i < 512; i += 256) ((float*)hsred)[i] = 0.f;

  float part[4][4];
#pragma unroll
  for (int m = 0; m < 4; ++m)
#pragma unroll
    for (int i = 0; i < 4; ++i) part[m][i] = 0.f;

  const int f4 = tid & 15;
  const int r0 = tid >> 4;
  const float* srcbase = hid + (size_t)(b * 512 + cb * 64) * 4096 + n * 512;
  unsigned short* xtbase = XT + (size_t)(b * 8 + n) * 512 * 512 + cb * 64;

  for (int jc = 0; jc < 8; ++jc) {
    __syncthreads();
#pragma unroll
    for (int m = 0; m < 4; ++m) {
      int r = r0 + 16 * m;
      float4 v = *(const float4*)(srcbase + (size_t)r * 4096 + jc * 64 + f4 * 4);
      T[r][f4 * 4 + 0] = v.x;  T[r][f4 * 4 + 1] = v.y;
      T[r][f4 * 4 + 2] = v.z;  T[r][f4 * 4 + 3] = v.w;
      part[m][0] += v.x; part[m][1] += v.y; part[m][2] += v.z; part[m][3] += v.w;
    }
    __syncthreads();
#pragma unroll
    for (int p = 0; p < 2; ++p) {
      int jl = (tid >> 3) + p * 32;
      int o = tid & 7;
      unsigned short t0 = f2bf(T[o * 8 + 0][jl]);
      unsigned short t1 = f2bf(T[o * 8 + 1][jl]);
      unsigned short t2 = f2bf(T[o * 8 + 2][jl]);
      unsigned short t3 = f2bf(T[o * 8 + 3][jl]);
      unsigned short t4 = f2bf(T[o * 8 + 4][jl]);
      unsigned short t5 = f2bf(T[o * 8 + 5][jl]);
      unsigned short t6 = f2bf(T[o * 8 + 6][jl]);
      unsigned short t7 = f2bf(T[o * 8 + 7][jl]);
      uint4 pk;
      pk.x = (unsigned)t0 | ((unsigned)t1 << 16);
      pk.y = (unsigned)t2 | ((unsigned)t3 << 16);
      pk.z = (unsigned)t4 | ((unsigned)t5 << 16);
      pk.w = (unsigned)t6 | ((unsigned)t7 << 16);
      *(uint4*)(xtbase + (size_t)(jc * 64 + jl) * 512 + o * 8) = pk;
    }
  }
  __syncthreads();
  {
    int gbase = (tid & 1) * 4;
#pragma unroll
    for (int m = 0; m < 4; ++m) {
      int r = r0 + 16 * m;
#pragma unroll
      for (int i = 0; i < 4; ++i) atomicAdd(&hsred[r][gbase + i], part[m][i]);
    }
  }
  __syncthreads();
  float* hout = hrsum + (size_t)(b * 8 + n) * 8 * 512 + cb * 64;
  for (int i = tid; i < 512; i += 256) {
    int g = i >> 6, r = i & 63;
    hout[(size_t)g * 512 + r] = hsred[r][g];
  }
}

// ---------------- kernel 3: K2 = hrsum@Wk^T + 64*bk ; qs = (guide@Wq^T+bq)/8 -
__global__ __launch_bounds__(256) void k_k2(const float* __restrict__ hrsum,
                                            const float* __restrict__ Wk,
                                            const float* __restrict__ bk,
                                            const float* __restrict__ guide,
                                            const float* __restrict__ Wq,
                                            const float* __restrict__ bq,
                                            float* __restrict__ K2,
                                            float* __restrict__ qs) {
  int bid = blockIdx.x;
  int rt = bid >> 4, ct = bid & 15;
  bool isQ = (rt == 16);
  const float* A = isQ ? guide : (hrsum + (size_t)rt * 32 * 512);
  const float* Bm = isQ ? Wq : Wk;
  int arows = isQ ? 8 : 32;
  int tid = threadIdx.x;
  __shared__ float Ah[32][36];
  __shared__ float Bh[32][36];
  int r = tid >> 3, f = tid & 7;
  int oy = (tid >> 4) * 2, ox = (tid & 15) * 2;
  float a00 = 0.f, a01 = 0.f, a10 = 0.f, a11 = 0.f;

  for (int kc = 0; kc < 16; ++kc) {
    __syncthreads();
    float4 av = (r < arows) ? *(const float4*)(A + (size_t)r * 512 + kc * 32 + f * 4)
                            : make_float4(0.f, 0.f, 0.f, 0.f);
    *(float4*)(&Ah[r][f * 4]) = av;
    float4 bv = *(const float4*)(Bm + (size_t)(ct * 32 + r) * 512 + kc * 32 + f * 4);
    *(float4*)(&Bh[r][f * 4]) = bv;
    __syncthreads();
#pragma unroll
    for (int kk = 0; kk < 32; kk += 4) {
      float4 x0 = *(float4*)(&Ah[oy][kk]);
      float4 x1 = *(float4*)(&Ah[oy + 1][kk]);
      float4 y0 = *(float4*)(&Bh[ox][kk]);
      float4 y1 = *(float4*)(&Bh[ox + 1][kk]);
      a00 += x0.x * y0.x + x0.y * y0.y + x0.z * y0.z + x0.w * y0.w;
      a01 += x0.x * y1.x + x0.y * y1.y + x0.z * y1.z + x0.w * y1.w;
      a10 += x1.x * y0.x + x1.y * y0.y + x1.z * y0.z + x1.w * y0.w;
      a11 += x1.x * y1.x + x1.y * y1.y + x1.z * y1.z + x1.w * y1.w;
    }
  }
  int c0 = ct * 32 + ox;
  if (!isQ) {
    int row0 = rt * 32 + oy;
    K2[(size_t)row0 * 512 + c0]           = a00 + 64.f * bk[c0];
    K2[(size_t)row0 * 512 + c0 + 1]       = a01 + 64.f * bk[c0 + 1];
    K2[(size_t)(row0 + 1) * 512 + c0]     = a10 + 64.f * bk[c0];
    K2[(size_t)(row0 + 1) * 512 + c0 + 1] = a11 + 64.f * bk[c0 + 1];
  } else if (oy < 8) {
    const float scale = 0.125f;
    qs[(size_t)oy * 512 + c0]           = (a00 + bq[c0]) * scale;
    qs[(size_t)oy * 512 + c0 + 1]       = (a01 + bq[c0 + 1]) * scale;
    qs[(size_t)(oy + 1) * 512 + c0]     = (a10 + bq[c0]) * scale;
    qs[(size_t)(oy + 1) * 512 + c0 + 1] = (a11 + bq[c0 + 1]) * scale;
  }
}

// ---------------- kernel 4: fused V-GEMM + rank-1 softmax + PV ---------------
// grid 512 = slab(64) * g(8), XCD-grouped; 512 threads = 8 waves, wave w = e.
// LDS: B0 [0,8K) B1 [8K,16K) Vpriv[w] [16K + w*8K, +8K). Total 80KB -> 2 blk/CU.
__global__ __launch_bounds__(512, 4) void k_fused(
    const unsigned short* __restrict__ XT, const unsigned short* __restrict__ Wvb,
    const float* __restrict__ K2, const float* __restrict__ qs,
    const float* __restrict__ bv, float* __restrict__ out) {
  // XCD-aware swizzle: XCD x gets slabs [8x, 8x+8), all 8 g's per slab.
  int p = blockIdx.x;
  int xcd = p & 7, idx = p >> 3;
  int slab = xcd * 8 + (idx & 7);
  int g = idx >> 3;
  int n = slab & 7, b = slab >> 3;

  int tid = threadIdx.x;
  int w = tid >> 6, l = tid & 63;
  int l15 = l & 15, l4 = l >> 4, lr = l >> 3, lc = l & 7;

  __shared__ __align__(16) unsigned char smem[81920];
  unsigned char* Vp = smem + 16384 + w * 8192;   // wave-private V [64 dd][128B]

  const unsigned swzel = (unsigned)((lc ^ lr) << 3);  // pre-swizzled src col
  const unsigned short* bsrc = XT + (size_t)slab * 512 * 512;
  const unsigned short* wbase = Wvb + (size_t)(w * 64 + l15) * 512 + l4 * 8;
  const int brow = 8 * (w * 8 + lr) + g;   // XT j-row this lane-group stages

  // scalars for phase 2 (issued first => oldest vmcnt ops)
  float alpha = qs[(size_t)b * 512 + w * 64 + l];            // lane = qq
  float beta  = K2[(size_t)(slab * 8 + g) * 512 + w * 64 + l]; // lane = kk
  float bvreg = bv[w * 64 + l];                              // lane = kk

  // B prologue: tiles 0,1
  gload16(bsrc + (size_t)brow * 512 + 0 * 64 + swzel, smem + 0 * 8192 + w * 1024);
  gload16(bsrc + (size_t)brow * 512 + 1 * 64 + swzel, smem + 1 * 8192 + w * 1024);

  // A prefetch for step s=0 (K32-steps s = kc*2+ks)
  bf16x8_t af[2][4];
#pragma unroll
  for (int mt = 0; mt < 4; ++mt)
    af[0][mt] = *(const bf16x8_t*)(wbase + mt * 16 * 512);

  f32x4_t acc[4][4];
#pragma unroll
  for (int i = 0; i < 4; ++i)
#pragma unroll
    for (int j = 0; j < 4; ++j) acc[i][j] = (f32x4_t){0.f, 0.f, 0.f, 0.f};

#pragma unroll
  for (int kc = 0; kc < 8; ++kc) {
    // outstanding (newer than B(kc)): B(kc+1)[1] + A-prefetch group[4] = 5
    if (kc < 7) asm volatile("s_waitcnt vmcnt(5)" ::: "memory");
    else        asm volatile("s_waitcnt vmcnt(4)" ::: "memory");
    __builtin_amdgcn_s_barrier();
    asm volatile("" ::: "memory");
    unsigned char* Bb = smem + (kc & 1) * 8192;
#pragma unroll
    for (int ks = 0; ks < 2; ++ks) {
      const int s = kc * 2 + ks;
      if (s < 15) {  // prefetch A for next K32-step into the other reg set
#pragma unroll
        for (int mt = 0; mt < 4; ++mt)
          af[(s + 1) & 1][mt] =
              *(const bf16x8_t*)(wbase + mt * 16 * 512 + (s + 1) * 32);
      }
      bf16x8_t bfr[4];
#pragma unroll
      for (int nt = 0; nt < 4; ++nt) {
        unsigned row = (unsigned)(nt * 16 + l15);
        bfr[nt] = *(const bf16x8_t*)(Bb + row * 128 +
                                     ((unsigned)(ks * 64 + l4 * 16) ^ ((row & 7) << 4)));
      }
      __builtin_amdgcn_s_setprio(1);
#pragma unroll
      for (int mt = 0; mt < 4; ++mt)
#pragma unroll
        for (int nt = 0; nt < 4; ++nt)
          acc[mt][nt] = __builtin_amdgcn_mfma_f32_16x16x32_bf16(
              af[s & 1][mt], bfr[nt], acc[mt][nt], 0, 0, 0);
      __builtin_amdgcn_s_setprio(0);
    }
    asm volatile("" ::: "memory");
    __builtin_amdgcn_s_barrier();
    asm volatile("" ::: "memory");
    if (kc < 6)
      gload16(bsrc + (size_t)brow * 512 + (kc + 2) * 64 + swzel,
              smem + (kc & 1) * 8192 + w * 1024);
  }

  // ---- spill V + bias -> wave-private Vp[dd][kk] bf16 (XOR-swizzled) ----
  // acc lane layout: V[kk = mt*16 + l4*4 + r][dd = nt*16 + l15]
#pragma unroll
  for (int mt = 0; mt < 4; ++mt) {
    float bq0 = __shfl(bvreg, mt * 16 + l4 * 4 + 0);
    float bq1 = __shfl(bvreg, mt * 16 + l4 * 4 + 1);
    float bq2 = __shfl(bvreg, mt * 16 + l4 * 4 + 2);
    float bq3 = __shfl(bvreg, mt * 16 + l4 * 4 + 3);
#pragma unroll
    for (int nt = 0; nt < 4; ++nt) {
      unsigned dd = (unsigned)(nt * 16 + l15);
      uint2 pk;
      pk.x = (unsigned)f2bf(acc[mt][nt][0] + bq0) |
             ((unsigned)f2bf(acc[mt][nt][1] + bq1) << 16);
      pk.y = (unsigned)f2bf(acc[mt][nt][2] + bq2) |
             ((unsigned)f2bf(acc[mt][nt][3] + bq3) << 16);
      *(uint2*)(Vp + dd * 128 +
                ((unsigned)(mt * 32 + l4 * 8) ^ ((dd & 7) << 4))) = pk;
    }
  }

  // ---- phase 2: rank-1 softmax in-register + PV (wave-local, no barriers) --
  float bmax = beta, bmin = beta;
#pragma unroll
  for (int o = 32; o >= 1; o >>= 1) {
    bmax = fmaxf(bmax, __shfl_xor(bmax, o));
    bmin = fminf(bmin, __shfl_xor(bmin, o));
  }
  float m = alpha >= 0.f ? alpha * bmax : alpha * bmin;
  float ssum = 0.f;
#pragma unroll 8
  for (int kk = 0; kk < 64; ++kk)
    ssum += __expf(fmaf(alpha, __shfl(beta, kk), -m));
  float inv = 1.0f / ssum;

  f32x4_t acc2[4][4];
#pragma unroll
  for (int i = 0; i < 4; ++i)
#pragma unroll
    for (int j = 0; j < 4; ++j) acc2[i][j] = (f32x4_t){0.f, 0.f, 0.f, 0.f};

#pragma unroll
  for (int ks = 0; ks < 2; ++ks) {
    bf16x8_t va[4];
#pragma unroll
    for (int mt = 0; mt < 4; ++mt) {   // A[dd][kk] from Vp
      unsigned dd = (unsigned)(mt * 16 + l15);
      va[mt] = *(const bf16x8_t*)(Vp + dd * 128 +
                ((unsigned)(ks * 64 + l4 * 16) ^ ((dd & 7) << 4)));
    }
    float bvv[8];
#pragma unroll
    for (int i = 0; i < 8; ++i) bvv[i] = __shfl(beta, ks * 32 + l4 * 8 + i);
    bf16x8_t pb[4];
#pragma unroll
    for (int nt = 0; nt < 4; ++nt) {   // B[kk][qq] built in registers
      int qq = nt * 16 + l15;
      float aq = __shfl(alpha, qq);
      float mq = __shfl(m, qq);
      float iq = __shfl(inv, qq);
      bf16x8_t pp;
#pragma unroll
      for (int i = 0; i < 8; ++i)
        pp[i] = (short)f2bf(__expf(fmaf(aq, bvv[i], -mq)) * iq);
      pb[nt] = pp;
    }
#pragma unroll
    for (int mt = 0; mt < 4; ++mt)
#pragma unroll
      for (int nt = 0; nt < 4; ++nt)
        acc2[mt][nt] = __builtin_amdgcn_mfma_f32_16x16x32_bf16(
            va[mt], pb[nt], acc2[mt][nt], 0, 0, 0);
  }

  // ---- stores: D[m=dd][n=qq], contiguous 64B per 16 lanes ----
#pragma unroll
  for (int mt = 0; mt < 4; ++mt) {
#pragma unroll
    for (int r = 0; r < 4; ++r) {
      int dd = mt * 16 + l4 * 4 + r;
      size_t base = (((size_t)(b * 512 + n * 64 + dd)) * 64 + (g * 8 + w)) * 64;
#pragma unroll
      for (int nt = 0; nt < 4; ++nt)
        out[base + nt * 16 + l15] = acc2[mt][nt][r];
    }
  }
}

// ---------------------------------------------------------------------------
extern "C" void kernel_launch(void* const* d_in, const int* in_sizes, int n_in,
                              void* d_out, int out_size, void* d_ws, size_t ws_size,
                              hipStream_t stream) {
  const float* guide = (const float*)d_in[0];
  const float* hid   = (const float*)d_in[1];
  const float* Wq    = (const float*)d_in[2];
  const float* bq    = (const float*)d_in[3];
  const float* Wk    = (const float*)d_in[4];
  const float* bk    = (const float*)d_in[5];
  const float* Wv    = (const float*)d_in[6];
  const float* bv    = (const float*)d_in[7];
  float* out = (float*)d_out;

  char* ws = (char*)d_ws;
  unsigned short* XT  = (unsigned short*)(ws);             // 33,554,432 B
  unsigned short* Wvb = (unsigned short*)(ws + 33554432);  //    524,288 B
  float* hrsum        = (float*)(ws + 34078720);           //  1,048,576 B
  float* K2           = (float*)(ws + 35127296);           //  1,048,576 B
  float* qs           = (float*)(ws + 36175872);           //     16,384 B

  k_trans<<<528, 256, 0, stream>>>(hid, XT, hrsum, Wv, Wvb);
  k_k2<<<272, 256, 0, stream>>>(hrsum, Wk, bk, guide, Wq, bq, K2, qs);
  k_fused<<<512, 512, 0, stream>>>(XT, Wvb, K2, qs, bv, out);
}